// Round 10
// baseline (150.350 us; speedup 1.0000x reference)
//
#include <hip/hip_runtime.h>
#include <stdint.h>

typedef __attribute__((ext_vector_type(4))) float f32x4;
typedef __attribute__((ext_vector_type(8))) short bf16x8;
typedef __attribute__((ext_vector_type(4))) unsigned short u16x4;

#define AS1(p) ((const __attribute__((address_space(1))) void*)(p))
#define AS3(p) ((__attribute__((address_space(3))) void*)(p))

__device__ __forceinline__ unsigned short f2bf(float f){
  unsigned u = __builtin_bit_cast(unsigned, f);
  u += 0x7FFF + ((u >> 16) & 1);     // round-to-nearest-even
  return (unsigned short)(u >> 16);
}

// ---------- transpose + cast: in f32 [R][C] -> out bf16 [C][R] ----------
__global__ __launch_bounds__(256) void k_transpose_cast(const float* __restrict__ in,
                                                        unsigned short* __restrict__ out,
                                                        int R, int C){
  __shared__ float tile[32][33];
  int tx = threadIdx.x & 31, ty = threadIdx.x >> 5;       // 32 x 8
  int c0 = blockIdx.x*32, r0 = blockIdx.y*32;
  #pragma unroll
  for (int i = 0; i < 4; i++)
    tile[ty + i*8][tx] = in[(size_t)(r0 + ty + i*8)*C + c0 + tx];
  __syncthreads();
  #pragma unroll
  for (int i = 0; i < 4; i++)
    out[(size_t)(c0 + ty + i*8)*R + r0 + tx] = f2bf(tile[tx][ty + i*8]);
}

// ============ bf16 GEMM, 128x128 tile, 3-deep counted-vmcnt pipeline ========
// MLP-starvation fix: 3 LDS buffers, tiles t+1,t+2 always in flight; per step
// {vmcnt(4) [NOT 0] -> s_barrier -> STAGE(t+2) -> ds_read(t) -> MFMA}.
// Chunk XOR-swizzle (c ^ (row>>1)&3) at stage-source AND read, dest linear.
template<bool RELU, bool OUTBF16>
__global__ __launch_bounds__(256) void k_gemm(const unsigned short* __restrict__ A,
                                              const unsigned short* __restrict__ Bt,
                                              const float* __restrict__ bias,
                                              void* __restrict__ out, int K, int N){
  __shared__ short As[3][128*32];
  __shared__ short Bs[3][128*32];
  const int tid  = threadIdx.x;
  const int lane = tid & 63, wid = tid >> 6;
  const int wr = wid >> 1, wc = wid & 1;
  const int l15 = lane & 15, lk = lane >> 4;
  const int bm = blockIdx.x, bn = blockIdx.y;

  const int srow = tid >> 2;
  const int slk  = (tid & 3) ^ ((srow >> 1) & 3);
  const unsigned short* Ab = A  + (size_t)bm*128*K + (size_t)srow*K + slk*8;
  const unsigned short* Bb = Bt + (size_t)bn*128*K + (size_t)srow*K + slk*8;

  f32x4 acc[4][4];
  #pragma unroll
  for (int i = 0; i < 4; i++)
    #pragma unroll
    for (int j = 0; j < 4; j++) acc[i][j] = (f32x4){0.f,0.f,0.f,0.f};

  const int nt = K >> 5;

#define STAGE(t, bb) do{ int k0_ = (t) << 5; \
  __builtin_amdgcn_global_load_lds(AS1(Ab + k0_),                AS3(&As[bb][tid*8]),        16, 0, 0); \
  __builtin_amdgcn_global_load_lds(AS1(Ab + (size_t)64*K + k0_), AS3(&As[bb][tid*8 + 2048]), 16, 0, 0); \
  __builtin_amdgcn_global_load_lds(AS1(Bb + k0_),                AS3(&Bs[bb][tid*8]),        16, 0, 0); \
  __builtin_amdgcn_global_load_lds(AS1(Bb + (size_t)64*K + k0_), AS3(&Bs[bb][tid*8 + 2048]), 16, 0, 0); \
}while(0)

  STAGE(0, 0);
  STAGE(1, 1);
  int b = 0;
  for (int t = 0; t < nt; ++t){
    if (t + 1 < nt) asm volatile("s_waitcnt vmcnt(4)" ::: "memory");
    else            asm volatile("s_waitcnt vmcnt(0)" ::: "memory");
    __builtin_amdgcn_s_barrier();
    __builtin_amdgcn_sched_barrier(0);
    if (t + 2 < nt){
      int nb = b + 2; if (nb >= 3) nb -= 3;
      STAGE(t + 2, nb);
    }
    bf16x8 af[4], bg[4];
    #pragma unroll
    for (int i = 0; i < 4; i++){
      int R = wr*64 + i*16 + l15;
      af[i] = *(const bf16x8*)&As[b][R*32 + (lk ^ ((R >> 1) & 3))*8];
    }
    #pragma unroll
    for (int j = 0; j < 4; j++){
      int R = wc*64 + j*16 + l15;
      bg[j] = *(const bf16x8*)&Bs[b][R*32 + (lk ^ ((R >> 1) & 3))*8];
    }
    #pragma unroll
    for (int i = 0; i < 4; i++)
      #pragma unroll
      for (int j = 0; j < 4; j++)
        acc[i][j] = __builtin_amdgcn_mfma_f32_16x16x32_bf16(af[i], bg[j], acc[i][j], 0, 0, 0);
    b = (b + 1 == 3) ? 0 : b + 1;
  }
#undef STAGE

  const int row0 = bm*128 + wr*64 + lk*4;
  const int col0 = bn*128 + wc*64 + l15;
  #pragma unroll
  for (int i = 0; i < 4; i++){
    #pragma unroll
    for (int j = 0; j < 4; j++){
      int col = col0 + j*16;
      float bv = bias[col];
      #pragma unroll
      for (int r = 0; r < 4; r++){
        int row = row0 + i*16 + r;
        float v = acc[i][j][r] + bv;
        if (RELU) v = fmaxf(v, 0.f);
        if (OUTBF16) ((unsigned short*)out)[(size_t)row*N + col] = f2bf(v);
        else         ((float*)out)[(size_t)row*N + col] = v;
      }
    }
  }
}

// ============ GEMM1: A is f32, staged raw into LDS (vmcnt-counted), =========
// converted to bf16 at fragment read (same f2bf RNE -> identical numerics).
__global__ __launch_bounds__(256) void k_gemm1(const float* __restrict__ A,
                                               const unsigned short* __restrict__ Bt,
                                               const float* __restrict__ bias,
                                               unsigned short* __restrict__ out,
                                               int K, int N){
  __shared__ float Af[3][128*32];   // 48 KB: f32 A tiles, 8 chunks/row swizzled
  __shared__ short Bs[3][128*32];   // 24 KB
  const int tid  = threadIdx.x;
  const int lane = tid & 63, wid = tid >> 6;
  const int wr = wid >> 1, wc = wid & 1;
  const int l15 = lane & 15, lk = lane >> 4;
  const int bm = blockIdx.x, bn = blockIdx.y;

  // A staging: issue i covers chunk g = i*256+tid -> row r = i*32+(tid>>3),
  // slot s = tid&7; source chunk = s ^ (r&7); dest linear (base+lane*16).
  const int ar = tid >> 3;
  const int ac = (tid & 7) ^ (ar & 7);
  const float* Abase = A + (size_t)bm*128*K + (size_t)ar*K + ac*4;
  const int srow = tid >> 2;
  const int slk  = (tid & 3) ^ ((srow >> 1) & 3);
  const unsigned short* Bb = Bt + (size_t)bn*128*K + (size_t)srow*K + slk*8;

  f32x4 acc[4][4];
  #pragma unroll
  for (int i = 0; i < 4; i++)
    #pragma unroll
    for (int j = 0; j < 4; j++) acc[i][j] = (f32x4){0.f,0.f,0.f,0.f};

  const int nt = K >> 5;

#define STAGE1(t, bb) do{ int k0_ = (t) << 5; \
  __builtin_amdgcn_global_load_lds(AS1(Abase + k0_),                AS3(&Af[bb][(0*256 + tid)*4]), 16, 0, 0); \
  __builtin_amdgcn_global_load_lds(AS1(Abase + (size_t)32*K + k0_), AS3(&Af[bb][(1*256 + tid)*4]), 16, 0, 0); \
  __builtin_amdgcn_global_load_lds(AS1(Abase + (size_t)64*K + k0_), AS3(&Af[bb][(2*256 + tid)*4]), 16, 0, 0); \
  __builtin_amdgcn_global_load_lds(AS1(Abase + (size_t)96*K + k0_), AS3(&Af[bb][(3*256 + tid)*4]), 16, 0, 0); \
  __builtin_amdgcn_global_load_lds(AS1(Bb + k0_),                   AS3(&Bs[bb][tid*8]),           16, 0, 0); \
  __builtin_amdgcn_global_load_lds(AS1(Bb + (size_t)64*K + k0_),    AS3(&Bs[bb][tid*8 + 2048]),    16, 0, 0); \
}while(0)

  STAGE1(0, 0);
  STAGE1(1, 1);
  int b = 0;
  for (int t = 0; t < nt; ++t){
    if (t + 1 < nt) asm volatile("s_waitcnt vmcnt(6)" ::: "memory");
    else            asm volatile("s_waitcnt vmcnt(0)" ::: "memory");
    __builtin_amdgcn_s_barrier();
    __builtin_amdgcn_sched_barrier(0);
    if (t + 2 < nt){
      int nb = b + 2; if (nb >= 3) nb -= 3;
      STAGE1(t + 2, nb);
    }
    bf16x8 af[4], bg[4];
    #pragma unroll
    for (int i = 0; i < 4; i++){
      int R = wr*64 + i*16 + l15;
      const float* rowp = &Af[b][R*32];
      int s0 = (2*lk)     ^ (R & 7);
      int s1 = (2*lk + 1) ^ (R & 7);
      f32x4 u0 = *(const f32x4*)(rowp + s0*4);
      f32x4 u1 = *(const f32x4*)(rowp + s1*4);
      #pragma unroll
      for (int j = 0; j < 4; j++){
        af[i][j]     = (short)f2bf(u0[j]);
        af[i][j + 4] = (short)f2bf(u1[j]);
      }
    }
    #pragma unroll
    for (int j = 0; j < 4; j++){
      int R = wc*64 + j*16 + l15;
      bg[j] = *(const bf16x8*)&Bs[b][R*32 + (lk ^ ((R >> 1) & 3))*8];
    }
    #pragma unroll
    for (int i = 0; i < 4; i++)
      #pragma unroll
      for (int j = 0; j < 4; j++)
        acc[i][j] = __builtin_amdgcn_mfma_f32_16x16x32_bf16(af[i], bg[j], acc[i][j], 0, 0, 0);
    b = (b + 1 == 3) ? 0 : b + 1;
  }
#undef STAGE1

  const int row0 = bm*128 + wr*64 + lk*4;
  const int col0 = bn*128 + wc*64 + l15;
  #pragma unroll
  for (int i = 0; i < 4; i++){
    #pragma unroll
    for (int j = 0; j < 4; j++){
      int col = col0 + j*16;
      float bv = bias[col];
      #pragma unroll
      for (int r = 0; r < 4; r++){
        int row = row0 + i*16 + r;
        float v = fmaxf(acc[i][j][r] + bv, 0.f);
        out[(size_t)row*N + col] = f2bf(v);
      }
    }
  }
}

// ================= KNN via uniform grid (counting sort + shell search) ======
#define GD 14
#define GD3 (GD*GD*GD)          // 2744 cells, ~3 pts/cell
#define NL 8192

__device__ __forceinline__ int cellcoord(float x){
  int c = (int)(x * (float)GD);
  return min(GD-1, max(0, c));
}

// zero the 4096-int hist (in-graph custom zero; rocclr fill kernel is noisy)
__global__ __launch_bounds__(64) void k_zero(int* __restrict__ p){
  #pragma unroll
  for (int i = 0; i < 16; i++)
    ((int4*)p)[threadIdx.x*16 + i] = (int4){0,0,0,0};
}

__global__ __launch_bounds__(256) void k_hist(const float* __restrict__ l_pos,
                                              int* __restrict__ hist){
  int i = blockIdx.x*256 + threadIdx.x;       // exactly 8192 threads
  float x = l_pos[3*i], y = l_pos[3*i+1], z = l_pos[3*i+2];
  int c = (cellcoord(z)*GD + cellcoord(y))*GD + cellcoord(x);
  atomicAdd(&hist[c], 1);
}

// exclusive prefix over 4096 (padded) hist entries -> cellStart + cursor copy
__global__ __launch_bounds__(1024) void k_scan(const int* __restrict__ hist,
                                               int* __restrict__ cellStart,
                                               int* __restrict__ cursor){
  __shared__ int s[1024];
  int t = threadIdx.x;
  int4 v = ((const int4*)hist)[t];
  int sum = v.x + v.y + v.z + v.w;
  s[t] = sum;
  __syncthreads();
  for (int off = 1; off < 1024; off <<= 1){
    int val = (t >= off) ? s[t-off] : 0;
    __syncthreads();
    s[t] += val;
    __syncthreads();
  }
  int base = s[t] - sum;                     // exclusive prefix of thread sums
  int4 cs;
  cs.x = base;
  cs.y = base + v.x;
  cs.z = base + v.x + v.y;
  cs.w = base + v.x + v.y + v.z;
  ((int4*)cellStart)[t] = cs;
  ((int4*)cursor)[t]    = cs;
}

__global__ __launch_bounds__(256) void k_scatter(const float* __restrict__ l_pos,
                                                 int* __restrict__ cursor,
                                                 float4* __restrict__ sorted){
  int i = blockIdx.x*256 + threadIdx.x;       // exactly 8192 threads
  float x = l_pos[3*i], y = l_pos[3*i+1], z = l_pos[3*i+2];
  int c = (cellcoord(z)*GD + cellcoord(y))*GD + cellcoord(x);
  int slot = atomicAdd(&cursor[c], 1);
  float4 q; q.x = x; q.y = y; q.z = z; q.w = __int_as_float(i);
  sorted[slot] = q;
}

// Dedup-safe + (d, index)-lexicographic insert: order-independent top-3
#define KNN_INS(dv, gi) \
  if (gi != i0 && gi != i1 && gi != i2 && \
      (dv < d2 || (dv == d2 && gi < i2))){ \
    if (dv < d1 || (dv == d1 && gi < i1)){ \
      d2 = d1; i2 = i1; \
      if (dv < d0 || (dv == d0 && gi < i0)){ d1 = d0; i1 = i0; d0 = dv; i0 = gi; } \
      else { d1 = dv; i1 = gi; } \
    } else { d2 = dv; i2 = gi; } \
  }

#define KNN_MERGE16() \
  _Pragma("unroll") \
  for (int m = 1; m < 16; m <<= 1){ \
    float e0 = __shfl_xor(d0, m), e1 = __shfl_xor(d1, m), e2 = __shfl_xor(d2, m); \
    int   j0 = __shfl_xor(i0, m), j1 = __shfl_xor(i1, m), j2 = __shfl_xor(i2, m); \
    KNN_INS(e0, j0); KNN_INS(e1, j1); KNN_INS(e2, j2); \
  }

// 16 lanes cooperate per h-point: 524288 threads = 8192 waves = 32 waves/CU
__global__ __launch_bounds__(256) void k_knn_grid(const float* __restrict__ h_pos,
                                                  const int* __restrict__ cellStart,
                                                  const float4* __restrict__ sorted,
                                                  float* __restrict__ w,
                                                  int* __restrict__ idx){
  const int t = blockIdx.x*256 + threadIdx.x;
  const int h = t >> 4, sl = t & 15;
  const float hx = h_pos[3*h], hy = h_pos[3*h+1], hz = h_pos[3*h+2];
  const int cx = cellcoord(hx), cy = cellcoord(hy), cz = cellcoord(hz);
  const float cs = 1.0f/(float)GD;
  float d0 = 3e38f, d1 = 3e38f, d2 = 3e38f;
  int   i0 = 0x7fffffff, i1 = 0x7fffffff, i2 = 0x7fffffff;

  for (int ci = sl; ci < 27; ci += 16){
    int dz = ci/9 - 1, dy = (ci - (ci/9)*9)/3 - 1, dx = ci % 3 - 1;
    int zz = cz+dz, yy = cy+dy, xx = cx+dx;
    if ((unsigned)zz >= GD || (unsigned)yy >= GD || (unsigned)xx >= GD) continue;
    int c = (zz*GD + yy)*GD + xx;
    int p0 = cellStart[c], p1 = cellStart[c+1];
    for (int p = p0; p < p1; p++){
      float4 qq = sorted[p];
      float ddx = hx - qq.x, ddy = hy - qq.y, ddz = hz - qq.z;
      float d = fmaf(ddx, ddx, fmaf(ddy, ddy, ddz*ddz));
      int gi = __float_as_int(qq.w);
      KNN_INS(d, gi);
    }
  }
  KNN_MERGE16();

  for (int r = 2; r < GD; r++){
    int rp = r - 1;
    float B = 3e38f;
    if (cx - rp > 0)      B = fminf(B, hx - (float)(cx-rp)*cs);
    if (cx + rp + 1 < GD) B = fminf(B, (float)(cx+rp+1)*cs - hx);
    if (cy - rp > 0)      B = fminf(B, hy - (float)(cy-rp)*cs);
    if (cy + rp + 1 < GD) B = fminf(B, (float)(cy+rp+1)*cs - hy);
    if (cz - rp > 0)      B = fminf(B, hz - (float)(cz-rp)*cs);
    if (cz + rp + 1 < GD) B = fminf(B, (float)(cz+rp+1)*cs - hz);
    if (d2 <= B*B) break;                     // group-uniform after merge

    int side = 2*r + 1, ss = side*side, tot = ss*side;
    for (int ci = sl; ci < tot; ci += 16){
      int dz = ci/ss - r;
      int rem = ci - (ci/ss)*ss;
      int dy = rem/side - r, dx = rem - (rem/side)*side - r;
      int adx = abs(dx), ady = abs(dy), adz = abs(dz);
      if (max(adx, max(ady, adz)) < r) continue;   // shell-exact: skip interior
      int zz = cz+dz, yy = cy+dy, xx = cx+dx;
      if ((unsigned)zz >= GD || (unsigned)yy >= GD || (unsigned)xx >= GD) continue;
      int c = (zz*GD + yy)*GD + xx;
      int p0 = cellStart[c], p1 = cellStart[c+1];
      for (int p = p0; p < p1; p++){
        float4 qq = sorted[p];
        float ddx = hx - qq.x, ddy = hy - qq.y, ddz = hz - qq.z;
        float d = fmaf(ddx, ddx, fmaf(ddy, ddy, ddz*ddz));
        int gi = __float_as_int(qq.w);
        KNN_INS(d, gi);
      }
    }
    KNN_MERGE16();
  }

  if (sl == 0){
    w[3*h+0] = 1.0f/fmaxf(d0, 1e-16f); idx[3*h+0] = i0;
    w[3*h+1] = 1.0f/fmaxf(d1, 1e-16f); idx[3*h+1] = i1;
    w[3*h+2] = 1.0f/fmaxf(d2, 1e-16f); idx[3*h+2] = i2;
  }
}

// ---------- KNN gather: l_y rows, weighted avg, add into out ----------
__global__ __launch_bounds__(256) void k_knn_gather(const float* __restrict__ w,
                                                    const int* __restrict__ idx,
                                                    const float* __restrict__ l_y,
                                                    float* __restrict__ out){
  const int t = blockIdx.x*256 + threadIdx.x;
  const int h = t >> 5, lane = t & 31;               // 32 lanes x float4 = 128 feats
  const float w0 = w[h*3+0], w1 = w[h*3+1], w2 = w[h*3+2];
  const int   j0 = idx[h*3+0], j1 = idx[h*3+1], j2 = idx[h*3+2];
  const f32x4* ly4 = (const f32x4*)l_y;
  f32x4 a = ly4[(size_t)j0*32 + lane]*w0
          + ly4[(size_t)j1*32 + lane]*w1
          + ly4[(size_t)j2*32 + lane]*w2;
  float inv = 1.0f/(w0 + w1 + w2);
  f32x4* o4 = (f32x4*)out;
  size_t oi = (size_t)h*32 + lane;
  o4[oi] = o4[oi] + a*inv;
}

extern "C" void kernel_launch(void* const* d_in, const int* in_sizes, int n_in,
                              void* d_out, int out_size, void* d_ws, size_t ws_size,
                              hipStream_t stream){
  const float* emb   = (const float*)d_in[0];
  const float* l_y   = (const float*)d_in[1];
  const float* l_pos = (const float*)d_in[2];
  const float* h_pos = (const float*)d_in[3];
  const float* W1    = (const float*)d_in[4];
  const float* b1    = (const float*)d_in[5];
  const float* W2    = (const float*)d_in[6];
  const float* b2    = (const float*)d_in[7];
  const float* W3    = (const float*)d_in[8];
  const float* b3    = (const float*)d_in[9];

  const int M = 32768, H = 512, O = 128;

  char* ws = (char*)d_ws;
  unsigned short* bufA = (unsigned short*)(ws);                  // 32 MB: X2
  unsigned short* bufB = (unsigned short*)(ws + 33554432);       // 32 MB: X1
  unsigned short* W1t  = (unsigned short*)(ws + 67108864);       // 512 KB
  unsigned short* W2t  = (unsigned short*)(ws + 67633152);       // 512 KB
  unsigned short* W3t  = (unsigned short*)(ws + 68157440);       // 128 KB
  int*    hist      = (int*)   (ws + 68288512);                  // 16 KB (4096 padded)
  int*    cellStart = (int*)   (ws + 68304896);                  // 16 KB
  int*    cursor    = (int*)   (ws + 68321280);                  // 16 KB
  float4* sorted    = (float4*)(ws + 68354048);                  // 128 KB
  float* wts = (float*)(ws + 74579968);                          // 384 KB
  int*   idx = (int*)  (ws + 74973184);                          // 384 KB

  // weight transposes (bf16 [N][K] for MFMA B-operand)
  k_transpose_cast<<<dim3(H/32, H/32), 256, 0, stream>>>(W1, W1t, H, H);
  k_transpose_cast<<<dim3(H/32, H/32), 256, 0, stream>>>(W2, W2t, H, H);
  k_transpose_cast<<<dim3(O/32, H/32), 256, 0, stream>>>(W3, W3t, H, O);

  // MLP
  k_gemm1<<<dim3(M/128, H/128), 256, 0, stream>>>(emb, W1t, b1, bufB, H, H);
  k_gemm<true,  true ><<<dim3(M/128, H/128), 256, 0, stream>>>(bufB, W2t, b2, bufA, H, H);
  k_gemm<false, false><<<dim3(M/128, O/128), 256, 0, stream>>>(bufA, W3t, b3, d_out, H, O);

  // KNN interpolate via uniform grid (+= into out)
  k_zero<<<dim3(1), 64, 0, stream>>>(hist);
  k_hist<<<dim3(NL/256), 256, 0, stream>>>(l_pos, hist);
  k_scan<<<dim3(1), 1024, 0, stream>>>(hist, cellStart, cursor);
  k_scatter<<<dim3(NL/256), 256, 0, stream>>>(l_pos, cursor, sorted);
  k_knn_grid<<<dim3(M*16/256), 256, 0, stream>>>(h_pos, cellStart, sorted, wts, idx);
  k_knn_gather<<<dim3(M*32/256), 256, 0, stream>>>(wts, idx, l_y, (float*)d_out);
}

// Round 11
// 139.497 us; speedup vs baseline: 1.0778x; 1.0778x over previous
//
#include <hip/hip_runtime.h>
#include <stdint.h>

typedef __attribute__((ext_vector_type(4))) float f32x4;
typedef __attribute__((ext_vector_type(8))) short bf16x8;
typedef __attribute__((ext_vector_type(4))) unsigned short u16x4;

#define AS1(p) ((const __attribute__((address_space(1))) void*)(p))
#define AS3(p) ((__attribute__((address_space(3))) void*)(p))

__device__ __forceinline__ unsigned short f2bf(float f){
  unsigned u = __builtin_bit_cast(unsigned, f);
  u += 0x7FFF + ((u >> 16) & 1);     // round-to-nearest-even
  return (unsigned short)(u >> 16);
}

template<int N> __device__ __forceinline__ void waitcnt_vm(){
  if constexpr (N==0) asm volatile("s_waitcnt vmcnt(0)" ::: "memory");
  else if constexpr (N==4) asm volatile("s_waitcnt vmcnt(4)" ::: "memory");
  else if constexpr (N==5) asm volatile("s_waitcnt vmcnt(5)" ::: "memory");
  else if constexpr (N==8) asm volatile("s_waitcnt vmcnt(8)" ::: "memory");
}

// ---------- transpose + cast: in f32 [R][C] -> out bf16 [C][R] ----------
__global__ __launch_bounds__(256) void k_transpose_cast(const float* __restrict__ in,
                                                        unsigned short* __restrict__ out,
                                                        int R, int C){
  __shared__ float tile[32][33];
  int tx = threadIdx.x & 31, ty = threadIdx.x >> 5;       // 32 x 8
  int c0 = blockIdx.x*32, r0 = blockIdx.y*32;
  #pragma unroll
  for (int i = 0; i < 4; i++)
    tile[ty + i*8][tx] = in[(size_t)(r0 + ty + i*8)*C + c0 + tx];
  __syncthreads();
  #pragma unroll
  for (int i = 0; i < 4; i++)
    out[(size_t)(c0 + ty + i*8)*R + r0 + tx] = f2bf(tile[tx][ty + i*8]);
}

// ======== Whole-N GEMM: block = 128 rows x NC cols (NC = full N) ===========
// out[M][NC] = act(A[M][K] @ Bt[NC][K]^T + bias). A read ONCE (no N re-reads);
// B (weights) L2-resident, re-read per block. 3-buf LDS, counted vmcnt.
// TW threads = WARPS_M(2) x WARPS_N(TW/128) waves, wave tile 64 x NC/WARPS_N.
// Swizzle: [row][32]shorts rows, chunk c stored at slot c ^ ((row>>1)&3),
// applied at stage-source and ds_read (dest linear for global_load_lds).
// AF32: A is f32; T14 reg-staging (load f32->regs early, f2bf+ds_write late).
template<int NC, int TW, int MINW, bool AF32, bool RELU, bool OUTBF16>
__global__ __launch_bounds__(TW, MINW) void k_gemm(const void* __restrict__ Av,
                                                   const unsigned short* __restrict__ Bt,
                                                   const float* __restrict__ bias,
                                                   void* __restrict__ out, int K){
  constexpr int WARPS_N = TW/128;          // 4 (TW=512) or 2 (TW=256)
  constexpr int WN = NC/WARPS_N;           // 128 or 64
  constexpr int NI = WN/16;                // 8 or 4
  constexpr int IA = AF32 ? 0 : (128*4)/TW;// bf16 A stage issues: 1 or 2
  constexpr int IB = (NC*4)/TW;            // B stage issues: 4 or 2
  constexpr int LS = IA + IB;              // loads per STAGE (bf16 path)

  __shared__ short As[3][128*32];
  __shared__ short Bs[3][NC*32];

  const int tid  = threadIdx.x;
  const int lane = tid & 63, wid = tid >> 6;
  const int wr = wid / WARPS_N, wc = wid % WARPS_N;
  const int l15 = lane & 15, lk = lane >> 4;
  const int bm = blockIdx.x;

  // ---- staging source pointers (inverse-swizzled chunk) ----
  const unsigned short* Bsrc[IB];
  #pragma unroll
  for (int q = 0; q < IB; q++){
    int row = q*(TW/4) + (tid >> 2);
    int ch  = (tid & 3) ^ ((row >> 1) & 3);
    Bsrc[q] = Bt + (size_t)row*K + ch*8;
  }
  const unsigned short* Asrc16[IA > 0 ? IA : 1];
  if constexpr (!AF32){
    #pragma unroll
    for (int a = 0; a < IA; a++){
      int row = a*(TW/4) + (tid >> 2);
      int ch  = (tid & 3) ^ ((row >> 1) & 3);
      Asrc16[a] = (const unsigned short*)Av + (size_t)bm*128*K + (size_t)row*K + ch*8;
    }
  }
  // AF32 reg-staging addresses (TW=512: one 16B bf16 chunk per thread)
  const float* A32 = (const float*)Av + (size_t)bm*128*K + (size_t)(tid>>2)*K + (size_t)(tid&3)*8;
  const int wch = ((tid & 3) ^ (((tid >> 2) >> 1) & 3));
  const int woff = (tid >> 2)*32 + wch*8;   // ds_write slot (shorts)

#define STAGE_B(t_, bb_) do{ int k0_ = (t_) << 5; _Pragma("unroll") \
  for (int q = 0; q < IB; q++) \
    __builtin_amdgcn_global_load_lds(AS1(Bsrc[q] + k0_), AS3(&Bs[bb_][(q*(TW/4))*32 + tid*8]), 16, 0, 0); \
}while(0)
#define STAGE_A16(t_, bb_) do{ int k0_ = (t_) << 5; _Pragma("unroll") \
  for (int a = 0; a < IA; a++) \
    __builtin_amdgcn_global_load_lds(AS1(Asrc16[a] + k0_), AS3(&As[bb_][(a*(TW/4))*32 + tid*8]), 16, 0, 0); \
}while(0)
#define A_CONV_WRITE(bb_) do{ bf16x8 p_; _Pragma("unroll") \
  for (int j_ = 0; j_ < 4; j_++){ p_[j_] = (short)f2bf(ra0[j_]); p_[j_+4] = (short)f2bf(ra1[j_]); } \
  *(bf16x8*)&As[bb_][woff] = p_; \
}while(0)

  f32x4 acc[4][NI];
  #pragma unroll
  for (int i = 0; i < 4; i++)
    #pragma unroll
    for (int j = 0; j < NI; j++) acc[i][j] = (f32x4){0.f,0.f,0.f,0.f};

  const int nt = K >> 5;                    // 16
  f32x4 ra0, ra1;

  // ---- prologue ----
  if constexpr (AF32){
    ra0 = *(const f32x4*)(A32);
    ra1 = *(const f32x4*)(A32 + 4);         // A(0): 2 loads
    STAGE_B(0, 0);                          // 4 loads
    STAGE_B(1, 1);                          // 4 loads
    waitcnt_vm<8>();                        // A(0) regs ready
    A_CONV_WRITE(0);
    waitcnt_vm<4>();                        // B(0) landed (B(1) still flying)
  } else {
    STAGE_A16(0, 0); STAGE_B(0, 0);
    STAGE_A16(1, 1); STAGE_B(1, 1);
  }

  int b = 0;
  for (int t = 0; t < nt; ++t){
    if constexpr (!AF32){
      if (t + 1 < nt) waitcnt_vm<LS>(); else waitcnt_vm<0>();
    }
    asm volatile("s_waitcnt lgkmcnt(0)" ::: "memory");
    __builtin_amdgcn_s_barrier();
    __builtin_amdgcn_sched_barrier(0);

    int nb = b + 2; if (nb >= 3) nb -= 3;
    if constexpr (AF32){
      if (t + 1 < nt){                       // A(t+1) -> regs (issued FIRST)
        int k1 = (t + 1) << 5;
        ra0 = *(const f32x4*)(A32 + k1);
        ra1 = *(const f32x4*)(A32 + k1 + 4);
      }
      if (t + 2 < nt) STAGE_B(t + 2, nb);
    } else {
      if (t + 2 < nt){ STAGE_A16(t + 2, nb); STAGE_B(t + 2, nb); }
    }

    // ---- compute tile t ----
    bf16x8 af[4], bg[NI];
    #pragma unroll
    for (int i = 0; i < 4; i++){
      int R = wr*64 + i*16 + l15;
      af[i] = *(const bf16x8*)&As[b][R*32 + (lk ^ ((R >> 1) & 3))*8];
    }
    #pragma unroll
    for (int j = 0; j < NI; j++){
      int R = wc*WN + j*16 + l15;
      bg[j] = *(const bf16x8*)&Bs[b][R*32 + (lk ^ ((R >> 1) & 3))*8];
    }
    #pragma unroll
    for (int i = 0; i < 4; i++)
      #pragma unroll
      for (int j = 0; j < NI; j++)
        acc[i][j] = __builtin_amdgcn_mfma_f32_16x16x32_bf16(af[i], bg[j], acc[i][j], 0, 0, 0);

    if constexpr (AF32){
      if (t + 1 < nt){
        if (t + 2 < nt) waitcnt_vm<4>(); else waitcnt_vm<0>();
        int wb = b + 1; if (wb >= 3) wb -= 3;
        A_CONV_WRITE(wb);
      }
    }
    b = (b + 1 == 3) ? 0 : b + 1;
  }
#undef STAGE_B
#undef STAGE_A16
#undef A_CONV_WRITE

  // ---- epilogue: C/D layout col = lane&15, row = (lane>>4)*4 + r ----
  const int row0 = bm*128 + wr*64 + lk*4;
  const int col0 = wc*WN + l15;
  #pragma unroll
  for (int i = 0; i < 4; i++){
    #pragma unroll
    for (int j = 0; j < NI; j++){
      int col = col0 + j*16;
      float bv = bias[col];
      #pragma unroll
      for (int r = 0; r < 4; r++){
        int row = row0 + i*16 + r;
        float v = acc[i][j][r] + bv;
        if (RELU) v = fmaxf(v, 0.f);
        if (OUTBF16) ((unsigned short*)out)[(size_t)row*NC + col] = f2bf(v);
        else         ((float*)out)[(size_t)row*NC + col] = v;
      }
    }
  }
}

// ================= KNN via uniform grid (counting sort + shell search) ======
#define GD 14
#define GD3 (GD*GD*GD)          // 2744 cells, ~3 pts/cell
#define NL 8192

__device__ __forceinline__ int cellcoord(float x){
  int c = (int)(x * (float)GD);
  return min(GD-1, max(0, c));
}

// zero the 4096-int hist (in-graph custom zero; rocclr fill kernel is noisy)
__global__ __launch_bounds__(64) void k_zero(int* __restrict__ p){
  #pragma unroll
  for (int i = 0; i < 16; i++)
    ((int4*)p)[threadIdx.x*16 + i] = (int4){0,0,0,0};
}

__global__ __launch_bounds__(256) void k_hist(const float* __restrict__ l_pos,
                                              int* __restrict__ hist){
  int i = blockIdx.x*256 + threadIdx.x;       // exactly 8192 threads
  float x = l_pos[3*i], y = l_pos[3*i+1], z = l_pos[3*i+2];
  int c = (cellcoord(z)*GD + cellcoord(y))*GD + cellcoord(x);
  atomicAdd(&hist[c], 1);
}

// exclusive prefix over 4096 (padded) hist entries -> cellStart + cursor copy
__global__ __launch_bounds__(1024) void k_scan(const int* __restrict__ hist,
                                               int* __restrict__ cellStart,
                                               int* __restrict__ cursor){
  __shared__ int s[1024];
  int t = threadIdx.x;
  int4 v = ((const int4*)hist)[t];
  int sum = v.x + v.y + v.z + v.w;
  s[t] = sum;
  __syncthreads();
  for (int off = 1; off < 1024; off <<= 1){
    int val = (t >= off) ? s[t-off] : 0;
    __syncthreads();
    s[t] += val;
    __syncthreads();
  }
  int base = s[t] - sum;                     // exclusive prefix of thread sums
  int4 cs;
  cs.x = base;
  cs.y = base + v.x;
  cs.z = base + v.x + v.y;
  cs.w = base + v.x + v.y + v.z;
  ((int4*)cellStart)[t] = cs;
  ((int4*)cursor)[t]    = cs;
}

__global__ __launch_bounds__(256) void k_scatter(const float* __restrict__ l_pos,
                                                 int* __restrict__ cursor,
                                                 float4* __restrict__ sorted){
  int i = blockIdx.x*256 + threadIdx.x;       // exactly 8192 threads
  float x = l_pos[3*i], y = l_pos[3*i+1], z = l_pos[3*i+2];
  int c = (cellcoord(z)*GD + cellcoord(y))*GD + cellcoord(x);
  int slot = atomicAdd(&cursor[c], 1);
  float4 q; q.x = x; q.y = y; q.z = z; q.w = __int_as_float(i);
  sorted[slot] = q;
}

// Dedup-safe + (d, index)-lexicographic insert: order-independent top-3
#define KNN_INS(dv, gi) \
  if (gi != i0 && gi != i1 && gi != i2 && \
      (dv < d2 || (dv == d2 && gi < i2))){ \
    if (dv < d1 || (dv == d1 && gi < i1)){ \
      d2 = d1; i2 = i1; \
      if (dv < d0 || (dv == d0 && gi < i0)){ d1 = d0; i1 = i0; d0 = dv; i0 = gi; } \
      else { d1 = dv; i1 = gi; } \
    } else { d2 = dv; i2 = gi; } \
  }

#define KNN_MERGE16() \
  _Pragma("unroll") \
  for (int m = 1; m < 16; m <<= 1){ \
    float e0 = __shfl_xor(d0, m), e1 = __shfl_xor(d1, m), e2 = __shfl_xor(d2, m); \
    int   j0 = __shfl_xor(i0, m), j1 = __shfl_xor(i1, m), j2 = __shfl_xor(i2, m); \
    KNN_INS(e0, j0); KNN_INS(e1, j1); KNN_INS(e2, j2); \
  }

// 16 lanes cooperate per h-point: 524288 threads = 8192 waves = 32 waves/CU
__global__ __launch_bounds__(256) void k_knn_grid(const float* __restrict__ h_pos,
                                                  const int* __restrict__ cellStart,
                                                  const float4* __restrict__ sorted,
                                                  float* __restrict__ w,
                                                  int* __restrict__ idx){
  const int t = blockIdx.x*256 + threadIdx.x;
  const int h = t >> 4, sl = t & 15;
  const float hx = h_pos[3*h], hy = h_pos[3*h+1], hz = h_pos[3*h+2];
  const int cx = cellcoord(hx), cy = cellcoord(hy), cz = cellcoord(hz);
  const float cs = 1.0f/(float)GD;
  float d0 = 3e38f, d1 = 3e38f, d2 = 3e38f;
  int   i0 = 0x7fffffff, i1 = 0x7fffffff, i2 = 0x7fffffff;

  for (int ci = sl; ci < 27; ci += 16){
    int dz = ci/9 - 1, dy = (ci - (ci/9)*9)/3 - 1, dx = ci % 3 - 1;
    int zz = cz+dz, yy = cy+dy, xx = cx+dx;
    if ((unsigned)zz >= GD || (unsigned)yy >= GD || (unsigned)xx >= GD) continue;
    int c = (zz*GD + yy)*GD + xx;
    int p0 = cellStart[c], p1 = cellStart[c+1];
    for (int p = p0; p < p1; p++){
      float4 qq = sorted[p];
      float ddx = hx - qq.x, ddy = hy - qq.y, ddz = hz - qq.z;
      float d = fmaf(ddx, ddx, fmaf(ddy, ddy, ddz*ddz));
      int gi = __float_as_int(qq.w);
      KNN_INS(d, gi);
    }
  }
  KNN_MERGE16();

  for (int r = 2; r < GD; r++){
    int rp = r - 1;
    float B = 3e38f;
    if (cx - rp > 0)      B = fminf(B, hx - (float)(cx-rp)*cs);
    if (cx + rp + 1 < GD) B = fminf(B, (float)(cx+rp+1)*cs - hx);
    if (cy - rp > 0)      B = fminf(B, hy - (float)(cy-rp)*cs);
    if (cy + rp + 1 < GD) B = fminf(B, (float)(cy+rp+1)*cs - hy);
    if (cz - rp > 0)      B = fminf(B, hz - (float)(cz-rp)*cs);
    if (cz + rp + 1 < GD) B = fminf(B, (float)(cz+rp+1)*cs - hz);
    if (d2 <= B*B) break;                     // group-uniform after merge

    int side = 2*r + 1, ss = side*side, tot = ss*side;
    for (int ci = sl; ci < tot; ci += 16){
      int dz = ci/ss - r;
      int rem = ci - (ci/ss)*ss;
      int dy = rem/side - r, dx = rem - (rem/side)*side - r;
      int adx = abs(dx), ady = abs(dy), adz = abs(dz);
      if (max(adx, max(ady, adz)) < r) continue;   // shell-exact: skip interior
      int zz = cz+dz, yy = cy+dy, xx = cx+dx;
      if ((unsigned)zz >= GD || (unsigned)yy >= GD || (unsigned)xx >= GD) continue;
      int c = (zz*GD + yy)*GD + xx;
      int p0 = cellStart[c], p1 = cellStart[c+1];
      for (int p = p0; p < p1; p++){
        float4 qq = sorted[p];
        float ddx = hx - qq.x, ddy = hy - qq.y, ddz = hz - qq.z;
        float d = fmaf(ddx, ddx, fmaf(ddy, ddy, ddz*ddz));
        int gi = __float_as_int(qq.w);
        KNN_INS(d, gi);
      }
    }
    KNN_MERGE16();
  }

  if (sl == 0){
    w[3*h+0] = 1.0f/fmaxf(d0, 1e-16f); idx[3*h+0] = i0;
    w[3*h+1] = 1.0f/fmaxf(d1, 1e-16f); idx[3*h+1] = i1;
    w[3*h+2] = 1.0f/fmaxf(d2, 1e-16f); idx[3*h+2] = i2;
  }
}

// ---------- KNN gather: l_y rows, weighted avg, add into out ----------
__global__ __launch_bounds__(256) void k_knn_gather(const float* __restrict__ w,
                                                    const int* __restrict__ idx,
                                                    const float* __restrict__ l_y,
                                                    float* __restrict__ out){
  const int t = blockIdx.x*256 + threadIdx.x;
  const int h = t >> 5, lane = t & 31;               // 32 lanes x float4 = 128 feats
  const float w0 = w[h*3+0], w1 = w[h*3+1], w2 = w[h*3+2];
  const int   j0 = idx[h*3+0], j1 = idx[h*3+1], j2 = idx[h*3+2];
  const f32x4* ly4 = (const f32x4*)l_y;
  f32x4 a = ly4[(size_t)j0*32 + lane]*w0
          + ly4[(size_t)j1*32 + lane]*w1
          + ly4[(size_t)j2*32 + lane]*w2;
  float inv = 1.0f/(w0 + w1 + w2);
  f32x4* o4 = (f32x4*)out;
  size_t oi = (size_t)h*32 + lane;
  o4[oi] = o4[oi] + a*inv;
}

extern "C" void kernel_launch(void* const* d_in, const int* in_sizes, int n_in,
                              void* d_out, int out_size, void* d_ws, size_t ws_size,
                              hipStream_t stream){
  const float* emb   = (const float*)d_in[0];
  const float* l_y   = (const float*)d_in[1];
  const float* l_pos = (const float*)d_in[2];
  const float* h_pos = (const float*)d_in[3];
  const float* W1    = (const float*)d_in[4];
  const float* b1    = (const float*)d_in[5];
  const float* W2    = (const float*)d_in[6];
  const float* b2    = (const float*)d_in[7];
  const float* W3    = (const float*)d_in[8];
  const float* b3    = (const float*)d_in[9];

  const int M = 32768, H = 512, O = 128;

  char* ws = (char*)d_ws;
  unsigned short* bufA = (unsigned short*)(ws);                  // 32 MB: X2
  unsigned short* bufB = (unsigned short*)(ws + 33554432);       // 32 MB: X1
  unsigned short* W1t  = (unsigned short*)(ws + 67108864);       // 512 KB
  unsigned short* W2t  = (unsigned short*)(ws + 67633152);       // 512 KB
  unsigned short* W3t  = (unsigned short*)(ws + 68157440);       // 128 KB
  int*    hist      = (int*)   (ws + 68288512);                  // 16 KB (4096 padded)
  int*    cellStart = (int*)   (ws + 68304896);                  // 16 KB
  int*    cursor    = (int*)   (ws + 68321280);                  // 16 KB
  float4* sorted    = (float4*)(ws + 68354048);                  // 128 KB
  float* wts = (float*)(ws + 74579968);                          // 384 KB
  int*   idx = (int*)  (ws + 74973184);                          // 384 KB

  // weight transposes (bf16 [N][K] for MFMA B-operand)
  k_transpose_cast<<<dim3(H/32, H/32), 256, 0, stream>>>(W1, W1t, H, H);
  k_transpose_cast<<<dim3(H/32, H/32), 256, 0, stream>>>(W2, W2t, H, H);
  k_transpose_cast<<<dim3(O/32, H/32), 256, 0, stream>>>(W3, W3t, H, O);

  // MLP: whole-N tiles, 256 blocks = 1/CU
  k_gemm<512, 512, 2, true,  true,  true ><<<dim3(M/128), 512, 0, stream>>>(emb,  W1t, b1, bufB, H);
  k_gemm<512, 512, 2, false, true,  true ><<<dim3(M/128), 512, 0, stream>>>(bufB, W2t, b2, bufA, H);
  k_gemm<128, 256, 3, false, false, false><<<dim3(M/128), 256, 0, stream>>>(bufA, W3t, b3, d_out, H);

  // KNN interpolate via uniform grid (+= into out)
  k_zero<<<dim3(1), 64, 0, stream>>>(hist);
  k_hist<<<dim3(NL/256), 256, 0, stream>>>(l_pos, hist);
  k_scan<<<dim3(1), 1024, 0, stream>>>(hist, cellStart, cursor);
  k_scatter<<<dim3(NL/256), 256, 0, stream>>>(l_pos, cursor, sorted);
  k_knn_grid<<<dim3(M*16/256), 256, 0, stream>>>(h_pos, cellStart, sorted, wts, idx);
  k_knn_gather<<<dim3(M*32/256), 256, 0, stream>>>(wts, idx, l_y, (float*)d_out);
}

// Round 12
// 122.880 us; speedup vs baseline: 1.2236x; 1.1352x over previous
//
#include <hip/hip_runtime.h>
#include <stdint.h>

typedef __attribute__((ext_vector_type(4))) float f32x4;
typedef __attribute__((ext_vector_type(8))) short bf16x8;
typedef __attribute__((ext_vector_type(4))) unsigned short u16x4;

#define AS1(p) ((const __attribute__((address_space(1))) void*)(p))
#define AS3(p) ((__attribute__((address_space(3))) void*)(p))

__device__ __forceinline__ unsigned short f2bf(float f){
  unsigned u = __builtin_bit_cast(unsigned, f);
  u += 0x7FFF + ((u >> 16) & 1);     // round-to-nearest-even
  return (unsigned short)(u >> 16);
}

template<int N> __device__ __forceinline__ void waitcnt_vm(){
  if constexpr (N==0) asm volatile("s_waitcnt vmcnt(0)" ::: "memory");
  else if constexpr (N==2) asm volatile("s_waitcnt vmcnt(2)" ::: "memory");
  else if constexpr (N==4) asm volatile("s_waitcnt vmcnt(4)" ::: "memory");
  else if constexpr (N==5) asm volatile("s_waitcnt vmcnt(5)" ::: "memory");
  else if constexpr (N==6) asm volatile("s_waitcnt vmcnt(6)" ::: "memory");
}

// ---------- batched transpose+cast: 3 weight matrices in one launch --------
__global__ __launch_bounds__(256) void k_transpose3(const float* __restrict__ W1,
                                                    const float* __restrict__ W2,
                                                    const float* __restrict__ W3,
                                                    unsigned short* __restrict__ W1t,
                                                    unsigned short* __restrict__ W2t,
                                                    unsigned short* __restrict__ W3t){
  const int z = blockIdx.z;
  const float* in; unsigned short* out; int R, C;
  if (z == 0){ in = W1; out = W1t; R = 512; C = 512; }
  else if (z == 1){ in = W2; out = W2t; R = 512; C = 512; }
  else { in = W3; out = W3t; R = 512; C = 128; if (blockIdx.x >= 4) return; }
  __shared__ float tile[32][33];
  int tx = threadIdx.x & 31, ty = threadIdx.x >> 5;       // 32 x 8
  int c0 = blockIdx.x*32, r0 = blockIdx.y*32;
  #pragma unroll
  for (int i = 0; i < 4; i++)
    tile[ty + i*8][tx] = in[(size_t)(r0 + ty + i*8)*C + c0 + tx];
  __syncthreads();
  #pragma unroll
  for (int i = 0; i < 4; i++)
    out[(size_t)(c0 + ty + i*8)*R + r0 + tx] = f2bf(tile[tx][ty + i*8]);
}

// ======== Whole-N GEMM: block = 128 rows x NC cols, 3-buf counted-vmcnt ====
// One barrier/step at tail; ds_reads at step top (fly during convergence);
// no sched_barrier pinning; setprio around MFMA cluster.
// Swizzle: chunk c of row stored at slot c ^ ((row>>1)&3) (both-sides).
// AF32: A f32, T14 reg-staged (load early, f2bf+ds_write at tail).
// ADDOUT: out[i] = acc + bias + out_prev[i] (fused knn-interp add).
template<int NC, int TW, bool AF32, bool RELU, bool OUTBF16, bool ADDOUT>
__global__ __launch_bounds__(TW, 2) void k_gemm(const void* __restrict__ Av,
                                                const unsigned short* __restrict__ Bt,
                                                const float* __restrict__ bias,
                                                void* __restrict__ out, int K){
  constexpr int WARPS_N = TW/128;
  constexpr int WN = NC/WARPS_N;
  constexpr int NI = WN/16;
  constexpr int IA = AF32 ? 0 : (128*4)/TW;
  constexpr int IB = (NC*4)/TW;
  constexpr int LS = IA + IB;

  __shared__ short As[3][128*32];
  __shared__ short Bs[3][NC*32];

  const int tid  = threadIdx.x;
  const int lane = tid & 63, wid = tid >> 6;
  const int wr = wid / WARPS_N, wc = wid % WARPS_N;
  const int l15 = lane & 15, lk = lane >> 4;
  const int bm = blockIdx.x;

  const unsigned short* Bsrc[IB];
  #pragma unroll
  for (int q = 0; q < IB; q++){
    int row = q*(TW/4) + (tid >> 2);
    int ch  = (tid & 3) ^ ((row >> 1) & 3);
    Bsrc[q] = Bt + (size_t)row*K + ch*8;
  }
  const unsigned short* Asrc16[IA > 0 ? IA : 1];
  if constexpr (!AF32){
    #pragma unroll
    for (int a = 0; a < IA; a++){
      int row = a*(TW/4) + (tid >> 2);
      int ch  = (tid & 3) ^ ((row >> 1) & 3);
      Asrc16[a] = (const unsigned short*)Av + (size_t)bm*128*K + (size_t)row*K + ch*8;
    }
  }
  const float* A32 = (const float*)Av + (size_t)bm*128*K + (size_t)(tid>>2)*K + (size_t)(tid&3)*8;
  const int woff = (tid >> 2)*32 + ((tid & 3) ^ (((tid >> 2) >> 1) & 3))*8;

#define STAGE_B(t_, bb_) do{ int k0_ = (t_) << 5; _Pragma("unroll") \
  for (int q = 0; q < IB; q++) \
    __builtin_amdgcn_global_load_lds(AS1(Bsrc[q] + k0_), AS3(&Bs[bb_][(q*(TW/4))*32 + tid*8]), 16, 0, 0); \
}while(0)
#define STAGE_A16(t_, bb_) do{ int k0_ = (t_) << 5; _Pragma("unroll") \
  for (int a = 0; a < IA; a++) \
    __builtin_amdgcn_global_load_lds(AS1(Asrc16[a] + k0_), AS3(&As[bb_][(a*(TW/4))*32 + tid*8]), 16, 0, 0); \
}while(0)
#define A_CONV_WRITE(bb_) do{ bf16x8 p_; _Pragma("unroll") \
  for (int j_ = 0; j_ < 4; j_++){ p_[j_] = (short)f2bf(ra0[j_]); p_[j_+4] = (short)f2bf(ra1[j_]); } \
  *(bf16x8*)&As[bb_][woff] = p_; \
}while(0)

  f32x4 acc[4][NI];
  #pragma unroll
  for (int i = 0; i < 4; i++)
    #pragma unroll
    for (int j = 0; j < NI; j++) acc[i][j] = (f32x4){0.f,0.f,0.f,0.f};

  const int nt = K >> 5;
  f32x4 ra0, ra1;

  // ---- prologue ----
  if constexpr (AF32){
    ra0 = *(const f32x4*)(A32);
    ra1 = *(const f32x4*)(A32 + 4);         // A(0): 2 (oldest)
    STAGE_B(0, 0);                          // B(0): 4
    STAGE_B(1, 1);                          // B(1): 4
    waitcnt_vm<4>();                        // A(0)+B(0) landed, B(1) flying
    A_CONV_WRITE(0);
    asm volatile("s_waitcnt lgkmcnt(0)" ::: "memory");
  } else {
    STAGE_A16(0, 0); STAGE_B(0, 0);
    STAGE_A16(1, 1); STAGE_B(1, 1);
    waitcnt_vm<LS>();                       // S(0) landed
  }
  __builtin_amdgcn_s_barrier();

  int b = 0;
  for (int t = 0; t < nt; ++t){
    // reads of tile t (safety est. by prev tail barrier); compiler interleaves
    bf16x8 af[4], bg[NI];
    #pragma unroll
    for (int i = 0; i < 4; i++){
      int R = wr*64 + i*16 + l15;
      af[i] = *(const bf16x8*)&As[b][R*32 + (lk ^ ((R >> 1) & 3))*8];
    }
    #pragma unroll
    for (int j = 0; j < NI; j++){
      int R = wc*WN + j*16 + l15;
      bg[j] = *(const bf16x8*)&Bs[b][R*32 + (lk ^ ((R >> 1) & 3))*8];
    }

    int b2 = b + 2; if (b2 >= 3) b2 -= 3;
    if constexpr (AF32){
      if (t + 1 < nt){
        int k1 = (t + 1) << 5;
        ra0 = *(const f32x4*)(A32 + k1);
        ra1 = *(const f32x4*)(A32 + k1 + 4);
      }
      if (t + 2 < nt) STAGE_B(t + 2, b2);
    } else {
      if (t + 2 < nt){ STAGE_A16(t + 2, b2); STAGE_B(t + 2, b2); }
    }

    __builtin_amdgcn_s_setprio(1);
    #pragma unroll
    for (int i = 0; i < 4; i++)
      #pragma unroll
      for (int j = 0; j < NI; j++)
        acc[i][j] = __builtin_amdgcn_mfma_f32_16x16x32_bf16(af[i], bg[j], acc[i][j], 0, 0, 0);
    __builtin_amdgcn_s_setprio(0);

    // tail: land S(t+1) (+A regs), write A(t+1), one barrier
    if (t + 2 < nt) waitcnt_vm<(AF32 ? 4 : LS)>();
    else            waitcnt_vm<0>();
    if constexpr (AF32){
      if (t + 1 < nt){
        int wb = b + 1; if (wb >= 3) wb -= 3;
        A_CONV_WRITE(wb);
      }
    }
    asm volatile("s_waitcnt lgkmcnt(0)" ::: "memory");
    __builtin_amdgcn_s_barrier();
    b = (b + 1 == 3) ? 0 : b + 1;
  }
#undef STAGE_B
#undef STAGE_A16
#undef A_CONV_WRITE

  // ---- epilogue: C/D layout col = lane&15, row = (lane>>4)*4 + r ----
  const int row0 = bm*128 + wr*64 + lk*4;
  const int col0 = wc*WN + l15;
  #pragma unroll
  for (int i = 0; i < 4; i++){
    #pragma unroll
    for (int j = 0; j < NI; j++){
      int col = col0 + j*16;
      float bv = bias[col];
      #pragma unroll
      for (int r = 0; r < 4; r++){
        int row = row0 + i*16 + r;
        float v = acc[i][j][r] + bv;
        if (RELU) v = fmaxf(v, 0.f);
        if (ADDOUT) v = v + ((const float*)out)[(size_t)row*NC + col];
        if (OUTBF16) ((unsigned short*)out)[(size_t)row*NC + col] = f2bf(v);
        else         ((float*)out)[(size_t)row*NC + col] = v;
      }
    }
  }
}

// ================= KNN via uniform grid (counting sort + shell search) ======
#define GD 14
#define GD3 (GD*GD*GD)          // 2744 cells, ~3 pts/cell
#define NL 8192

__device__ __forceinline__ int cellcoord(float x){
  int c = (int)(x * (float)GD);
  return min(GD-1, max(0, c));
}

__global__ __launch_bounds__(64) void k_zero(int* __restrict__ p){
  #pragma unroll
  for (int i = 0; i < 16; i++)
    ((int4*)p)[threadIdx.x*16 + i] = (int4){0,0,0,0};
}

__global__ __launch_bounds__(256) void k_hist(const float* __restrict__ l_pos,
                                              int* __restrict__ hist){
  int i = blockIdx.x*256 + threadIdx.x;       // exactly 8192 threads
  float x = l_pos[3*i], y = l_pos[3*i+1], z = l_pos[3*i+2];
  int c = (cellcoord(z)*GD + cellcoord(y))*GD + cellcoord(x);
  atomicAdd(&hist[c], 1);
}

__global__ __launch_bounds__(1024) void k_scan(const int* __restrict__ hist,
                                               int* __restrict__ cellStart,
                                               int* __restrict__ cursor){
  __shared__ int s[1024];
  int t = threadIdx.x;
  int4 v = ((const int4*)hist)[t];
  int sum = v.x + v.y + v.z + v.w;
  s[t] = sum;
  __syncthreads();
  for (int off = 1; off < 1024; off <<= 1){
    int val = (t >= off) ? s[t-off] : 0;
    __syncthreads();
    s[t] += val;
    __syncthreads();
  }
  int base = s[t] - sum;
  int4 cs;
  cs.x = base;
  cs.y = base + v.x;
  cs.z = base + v.x + v.y;
  cs.w = base + v.x + v.y + v.z;
  ((int4*)cellStart)[t] = cs;
  ((int4*)cursor)[t]    = cs;
}

__global__ __launch_bounds__(256) void k_scatter(const float* __restrict__ l_pos,
                                                 int* __restrict__ cursor,
                                                 float4* __restrict__ sorted){
  int i = blockIdx.x*256 + threadIdx.x;       // exactly 8192 threads
  float x = l_pos[3*i], y = l_pos[3*i+1], z = l_pos[3*i+2];
  int c = (cellcoord(z)*GD + cellcoord(y))*GD + cellcoord(x);
  int slot = atomicAdd(&cursor[c], 1);
  float4 q; q.x = x; q.y = y; q.z = z; q.w = __int_as_float(i);
  sorted[slot] = q;
}

// Dedup-safe + (d, index)-lexicographic insert: order-independent top-3
#define KNN_INS(dv, gi) \
  if (gi != i0 && gi != i1 && gi != i2 && \
      (dv < d2 || (dv == d2 && gi < i2))){ \
    if (dv < d1 || (dv == d1 && gi < i1)){ \
      d2 = d1; i2 = i1; \
      if (dv < d0 || (dv == d0 && gi < i0)){ d1 = d0; i1 = i0; d0 = dv; i0 = gi; } \
      else { d1 = dv; i1 = gi; } \
    } else { d2 = dv; i2 = gi; } \
  }

#define KNN_MERGE16() \
  _Pragma("unroll") \
  for (int m = 1; m < 16; m <<= 1){ \
    float e0 = __shfl_xor(d0, m), e1 = __shfl_xor(d1, m), e2 = __shfl_xor(d2, m); \
    int   j0 = __shfl_xor(i0, m), j1 = __shfl_xor(i1, m), j2 = __shfl_xor(i2, m); \
    KNN_INS(e0, j0); KNN_INS(e1, j1); KNN_INS(e2, j2); \
  }

// 16 lanes cooperate per h-point: 524288 threads = 8192 waves = 32 waves/CU
__global__ __launch_bounds__(256) void k_knn_grid(const float* __restrict__ h_pos,
                                                  const int* __restrict__ cellStart,
                                                  const float4* __restrict__ sorted,
                                                  float* __restrict__ w,
                                                  int* __restrict__ idx){
  const int t = blockIdx.x*256 + threadIdx.x;
  const int h = t >> 4, sl = t & 15;
  const float hx = h_pos[3*h], hy = h_pos[3*h+1], hz = h_pos[3*h+2];
  const int cx = cellcoord(hx), cy = cellcoord(hy), cz = cellcoord(hz);
  const float cs = 1.0f/(float)GD;
  float d0 = 3e38f, d1 = 3e38f, d2 = 3e38f;
  int   i0 = 0x7fffffff, i1 = 0x7fffffff, i2 = 0x7fffffff;

  for (int ci = sl; ci < 27; ci += 16){
    int dz = ci/9 - 1, dy = (ci - (ci/9)*9)/3 - 1, dx = ci % 3 - 1;
    int zz = cz+dz, yy = cy+dy, xx = cx+dx;
    if ((unsigned)zz >= GD || (unsigned)yy >= GD || (unsigned)xx >= GD) continue;
    int c = (zz*GD + yy)*GD + xx;
    int p0 = cellStart[c], p1 = cellStart[c+1];
    for (int p = p0; p < p1; p++){
      float4 qq = sorted[p];
      float ddx = hx - qq.x, ddy = hy - qq.y, ddz = hz - qq.z;
      float d = fmaf(ddx, ddx, fmaf(ddy, ddy, ddz*ddz));
      int gi = __float_as_int(qq.w);
      KNN_INS(d, gi);
    }
  }
  KNN_MERGE16();

  for (int r = 2; r < GD; r++){
    int rp = r - 1;
    float B = 3e38f;
    if (cx - rp > 0)      B = fminf(B, hx - (float)(cx-rp)*cs);
    if (cx + rp + 1 < GD) B = fminf(B, (float)(cx+rp+1)*cs - hx);
    if (cy - rp > 0)      B = fminf(B, hy - (float)(cy-rp)*cs);
    if (cy + rp + 1 < GD) B = fminf(B, (float)(cy+rp+1)*cs - hy);
    if (cz - rp > 0)      B = fminf(B, hz - (float)(cz-rp)*cs);
    if (cz + rp + 1 < GD) B = fminf(B, (float)(cz+rp+1)*cs - hz);
    if (d2 <= B*B) break;                     // group-uniform after merge

    int side = 2*r + 1, ss = side*side, tot = ss*side;
    for (int ci = sl; ci < tot; ci += 16){
      int dz = ci/ss - r;
      int rem = ci - (ci/ss)*ss;
      int dy = rem/side - r, dx = rem - (rem/side)*side - r;
      int adx = abs(dx), ady = abs(dy), adz = abs(dz);
      if (max(adx, max(ady, adz)) < r) continue;   // shell-exact: skip interior
      int zz = cz+dz, yy = cy+dy, xx = cx+dx;
      if ((unsigned)zz >= GD || (unsigned)yy >= GD || (unsigned)xx >= GD) continue;
      int c = (zz*GD + yy)*GD + xx;
      int p0 = cellStart[c], p1 = cellStart[c+1];
      for (int p = p0; p < p1; p++){
        float4 qq = sorted[p];
        float ddx = hx - qq.x, ddy = hy - qq.y, ddz = hz - qq.z;
        float d = fmaf(ddx, ddx, fmaf(ddy, ddy, ddz*ddz));
        int gi = __float_as_int(qq.w);
        KNN_INS(d, gi);
      }
    }
    KNN_MERGE16();
  }

  if (sl == 0){
    w[3*h+0] = 1.0f/fmaxf(d0, 1e-16f); idx[3*h+0] = i0;
    w[3*h+1] = 1.0f/fmaxf(d1, 1e-16f); idx[3*h+1] = i1;
    w[3*h+2] = 1.0f/fmaxf(d2, 1e-16f); idx[3*h+2] = i2;
  }
}

// ---------- KNN gather: WRITES interp into out (GEMM3 adds on top) ----------
__global__ __launch_bounds__(256) void k_knn_gather(const float* __restrict__ w,
                                                    const int* __restrict__ idx,
                                                    const float* __restrict__ l_y,
                                                    float* __restrict__ out){
  const int t = blockIdx.x*256 + threadIdx.x;
  const int h = t >> 5, lane = t & 31;               // 32 lanes x float4 = 128 feats
  const float w0 = w[h*3+0], w1 = w[h*3+1], w2 = w[h*3+2];
  const int   j0 = idx[h*3+0], j1 = idx[h*3+1], j2 = idx[h*3+2];
  const f32x4* ly4 = (const f32x4*)l_y;
  f32x4 a = ly4[(size_t)j0*32 + lane]*w0
          + ly4[(size_t)j1*32 + lane]*w1
          + ly4[(size_t)j2*32 + lane]*w2;
  float inv = 1.0f/(w0 + w1 + w2);
  ((f32x4*)out)[(size_t)h*32 + lane] = a*inv;
}

extern "C" void kernel_launch(void* const* d_in, const int* in_sizes, int n_in,
                              void* d_out, int out_size, void* d_ws, size_t ws_size,
                              hipStream_t stream){
  const float* emb   = (const float*)d_in[0];
  const float* l_y   = (const float*)d_in[1];
  const float* l_pos = (const float*)d_in[2];
  const float* h_pos = (const float*)d_in[3];
  const float* W1    = (const float*)d_in[4];
  const float* b1    = (const float*)d_in[5];
  const float* W2    = (const float*)d_in[6];
  const float* b2    = (const float*)d_in[7];
  const float* W3    = (const float*)d_in[8];
  const float* b3    = (const float*)d_in[9];

  const int M = 32768, H = 512;

  char* ws = (char*)d_ws;
  unsigned short* bufA = (unsigned short*)(ws);                  // 32 MB: X2
  unsigned short* bufB = (unsigned short*)(ws + 33554432);       // 32 MB: X1
  unsigned short* W1t  = (unsigned short*)(ws + 67108864);       // 512 KB
  unsigned short* W2t  = (unsigned short*)(ws + 67633152);       // 512 KB
  unsigned short* W3t  = (unsigned short*)(ws + 68157440);       // 128 KB
  int*    hist      = (int*)   (ws + 68288512);                  // 16 KB (4096 padded)
  int*    cellStart = (int*)   (ws + 68304896);                  // 16 KB
  int*    cursor    = (int*)   (ws + 68321280);                  // 16 KB
  float4* sorted    = (float4*)(ws + 68354048);                  // 128 KB
  float* wts = (float*)(ws + 74579968);                          // 384 KB
  int*   idx = (int*)  (ws + 74973184);                          // 384 KB

  // weight transposes (batched) — bf16 [N][K] for MFMA B-operand
  k_transpose3<<<dim3(16, 16, 3), 256, 0, stream>>>(W1, W2, W3, W1t, W2t, W3t);

  // KNN interpolate first; gather WRITES d_out (GEMM3 adds on top)
  k_zero<<<dim3(1), 64, 0, stream>>>(hist);
  k_hist<<<dim3(NL/256), 256, 0, stream>>>(l_pos, hist);
  k_scan<<<dim3(1), 1024, 0, stream>>>(hist, cellStart, cursor);
  k_scatter<<<dim3(NL/256), 256, 0, stream>>>(l_pos, cursor, sorted);
  k_knn_grid<<<dim3(M*16/256), 256, 0, stream>>>(h_pos, cellStart, sorted, wts, idx);
  k_knn_gather<<<dim3(M*32/256), 256, 0, stream>>>(wts, idx, l_y, (float*)d_out);

  // MLP: whole-N tiles, 256 blocks = 1/CU
  k_gemm<512, 512, true,  true,  true,  false><<<dim3(M/128), 512, 0, stream>>>(emb,  W1t, b1, bufB, H);
  k_gemm<512, 512, false, true,  true,  false><<<dim3(M/128), 512, 0, stream>>>(bufB, W2t, b2, bufA, H);
  k_gemm<128, 256, false, false, false, true ><<<dim3(M/128), 256, 0, stream>>>(bufA, W3t, b3, d_out, H);
}

// Round 13
// 120.014 us; speedup vs baseline: 1.2528x; 1.0239x over previous
//
#include <hip/hip_runtime.h>
#include <stdint.h>

typedef __attribute__((ext_vector_type(4))) float f32x4;
typedef __attribute__((ext_vector_type(8))) short bf16x8;
typedef __attribute__((ext_vector_type(4))) unsigned short u16x4;

#define AS1(p) ((const __attribute__((address_space(1))) void*)(p))
#define AS3(p) ((__attribute__((address_space(3))) void*)(p))

__device__ __forceinline__ unsigned short f2bf(float f){
  unsigned u = __builtin_bit_cast(unsigned, f);
  u += 0x7FFF + ((u >> 16) & 1);     // round-to-nearest-even
  return (unsigned short)(u >> 16);
}

template<int N> __device__ __forceinline__ void waitcnt_vm(){
  if constexpr (N==0) asm volatile("s_waitcnt vmcnt(0)" ::: "memory");
  else if constexpr (N==2) asm volatile("s_waitcnt vmcnt(2)" ::: "memory");
  else if constexpr (N==3) asm volatile("s_waitcnt vmcnt(3)" ::: "memory");
  else if constexpr (N==4) asm volatile("s_waitcnt vmcnt(4)" ::: "memory");
  else if constexpr (N==6) asm volatile("s_waitcnt vmcnt(6)" ::: "memory");
}

// ---------- batched transpose+cast: 3 weight matrices in one launch --------
__global__ __launch_bounds__(256) void k_transpose3(const float* __restrict__ W1,
                                                    const float* __restrict__ W2,
                                                    const float* __restrict__ W3,
                                                    unsigned short* __restrict__ W1t,
                                                    unsigned short* __restrict__ W2t,
                                                    unsigned short* __restrict__ W3t){
  const int z = blockIdx.z;
  const float* in; unsigned short* out; int R, C;
  if (z == 0){ in = W1; out = W1t; R = 512; C = 512; }
  else if (z == 1){ in = W2; out = W2t; R = 512; C = 512; }
  else { in = W3; out = W3t; R = 512; C = 128; if (blockIdx.x >= 4) return; }
  __shared__ float tile[32][33];
  int tx = threadIdx.x & 31, ty = threadIdx.x >> 5;       // 32 x 8
  int c0 = blockIdx.x*32, r0 = blockIdx.y*32;
  #pragma unroll
  for (int i = 0; i < 4; i++)
    tile[ty + i*8][tx] = in[(size_t)(r0 + ty + i*8)*C + c0 + tx];
  __syncthreads();
  #pragma unroll
  for (int i = 0; i < 4; i++)
    out[(size_t)(c0 + ty + i*8)*R + r0 + tx] = f2bf(tile[tx][ty + i*8]);
}

// ======== GEMM: block = BM rows x NC cols, 3-buf counted-vmcnt pipeline ====
// R13: NC halved (2 blocks/CU) to restore cross-block latency hiding (m114);
// loop body identical to R12 (verified): ds_reads at top, stage mid, setprio
// MFMA, counted vmcnt at tail, one barrier/step. Chunk swizzle both-sides.
// AF32: A f32, reg-staged (load early, f2bf+ds_write at tail).
// ADDOUT: out = acc + bias + out_prev (fused knn-interp add).
template<int BM, int NC, int TW, int MINW, bool AF32, bool RELU, bool OUTBF16, bool ADDOUT>
__global__ __launch_bounds__(TW, MINW) void k_gemm(const void* __restrict__ Av,
                                                   const unsigned short* __restrict__ Bt,
                                                   const float* __restrict__ bias,
                                                   void* __restrict__ out, int K){
  constexpr int WARPS_M = BM/64;
  constexpr int WARPS_N = (TW/64)/WARPS_M;
  constexpr int WN = NC/WARPS_N;
  constexpr int NI = WN/16;
  constexpr int IA = AF32 ? 0 : (BM*4)/TW;
  constexpr int IB = (NC*4)/TW;
  constexpr int LS = IA + IB;

  __shared__ short As[3][BM*32];
  __shared__ short Bs[3][NC*32];

  const int tid  = threadIdx.x;
  const int lane = tid & 63, wid = tid >> 6;
  const int wr = wid / WARPS_N, wc = wid % WARPS_N;
  const int l15 = lane & 15, lk = lane >> 4;
  const int bm = blockIdx.x, bn = blockIdx.y;

  const unsigned short* Bsrc[IB];
  #pragma unroll
  for (int q = 0; q < IB; q++){
    int row = q*(TW/4) + (tid >> 2);
    int ch  = (tid & 3) ^ ((row >> 1) & 3);
    Bsrc[q] = Bt + (size_t)bn*NC*K + (size_t)row*K + ch*8;
  }
  const unsigned short* Asrc16[IA > 0 ? IA : 1];
  if constexpr (!AF32){
    #pragma unroll
    for (int a = 0; a < IA; a++){
      int row = a*(TW/4) + (tid >> 2);
      int ch  = (tid & 3) ^ ((row >> 1) & 3);
      Asrc16[a] = (const unsigned short*)Av + (size_t)bm*BM*K + (size_t)row*K + ch*8;
    }
  }
  const float* A32 = (const float*)Av + (size_t)bm*BM*K + (size_t)(tid>>2)*K + (size_t)(tid&3)*8;
  const int woff = (tid >> 2)*32 + ((tid & 3) ^ (((tid >> 2) >> 1) & 3))*8;

#define STAGE_B(t_, bb_) do{ int k0_ = (t_) << 5; _Pragma("unroll") \
  for (int q = 0; q < IB; q++) \
    __builtin_amdgcn_global_load_lds(AS1(Bsrc[q] + k0_), AS3(&Bs[bb_][(q*(TW/4))*32 + tid*8]), 16, 0, 0); \
}while(0)
#define STAGE_A16(t_, bb_) do{ int k0_ = (t_) << 5; _Pragma("unroll") \
  for (int a = 0; a < IA; a++) \
    __builtin_amdgcn_global_load_lds(AS1(Asrc16[a] + k0_), AS3(&As[bb_][(a*(TW/4))*32 + tid*8]), 16, 0, 0); \
}while(0)
#define A_CONV_WRITE(bb_) do{ bf16x8 p_; _Pragma("unroll") \
  for (int j_ = 0; j_ < 4; j_++){ p_[j_] = (short)f2bf(ra0[j_]); p_[j_+4] = (short)f2bf(ra1[j_]); } \
  *(bf16x8*)&As[bb_][woff] = p_; \
}while(0)

  f32x4 acc[4][NI];
  #pragma unroll
  for (int i = 0; i < 4; i++)
    #pragma unroll
    for (int j = 0; j < NI; j++) acc[i][j] = (f32x4){0.f,0.f,0.f,0.f};

  const int nt = K >> 5;
  f32x4 ra0, ra1;

  // ---- prologue ----
  if constexpr (AF32){
    ra0 = *(const f32x4*)(A32);
    ra1 = *(const f32x4*)(A32 + 4);         // A(0): 2 (oldest)
    STAGE_B(0, 0);                          // B(0): IB
    STAGE_B(1, 1);                          // B(1): IB
    waitcnt_vm<IB>();                       // A(0)+B(0) landed, B(1) flying
    A_CONV_WRITE(0);
    asm volatile("s_waitcnt lgkmcnt(0)" ::: "memory");
  } else {
    STAGE_A16(0, 0); STAGE_B(0, 0);
    STAGE_A16(1, 1); STAGE_B(1, 1);
    waitcnt_vm<LS>();                       // S(0) landed
  }
  __builtin_amdgcn_s_barrier();

  int b = 0;
  for (int t = 0; t < nt; ++t){
    bf16x8 af[4], bg[NI];
    #pragma unroll
    for (int i = 0; i < 4; i++){
      int R = wr*64 + i*16 + l15;
      af[i] = *(const bf16x8*)&As[b][R*32 + (lk ^ ((R >> 1) & 3))*8];
    }
    #pragma unroll
    for (int j = 0; j < NI; j++){
      int R = wc*WN + j*16 + l15;
      bg[j] = *(const bf16x8*)&Bs[b][R*32 + (lk ^ ((R >> 1) & 3))*8];
    }

    int b2 = b + 2; if (b2 >= 3) b2 -= 3;
    if constexpr (AF32){
      if (t + 1 < nt){
        int k1 = (t + 1) << 5;
        ra0 = *(const f32x4*)(A32 + k1);
        ra1 = *(const f32x4*)(A32 + k1 + 4);
      }
      if (t + 2 < nt) STAGE_B(t + 2, b2);
    } else {
      if (t + 2 < nt){ STAGE_A16(t + 2, b2); STAGE_B(t + 2, b2); }
    }

    __builtin_amdgcn_s_setprio(1);
    #pragma unroll
    for (int i = 0; i < 4; i++)
      #pragma unroll
      for (int j = 0; j < NI; j++)
        acc[i][j] = __builtin_amdgcn_mfma_f32_16x16x32_bf16(af[i], bg[j], acc[i][j], 0, 0, 0);
    __builtin_amdgcn_s_setprio(0);

    if (t + 2 < nt) waitcnt_vm<(AF32 ? IB : LS)>();
    else            waitcnt_vm<0>();
    if constexpr (AF32){
      if (t + 1 < nt){
        int wb = b + 1; if (wb >= 3) wb -= 3;
        A_CONV_WRITE(wb);
      }
    }
    asm volatile("s_waitcnt lgkmcnt(0)" ::: "memory");
    __builtin_amdgcn_s_barrier();
    b = (b + 1 == 3) ? 0 : b + 1;
  }
#undef STAGE_B
#undef STAGE_A16
#undef A_CONV_WRITE

  // ---- epilogue: C/D layout col = lane&15, row = (lane>>4)*4 + r ----
  const int row0 = bm*BM + wr*64 + lk*4;
  const int col0 = bn*NC + wc*WN + l15;
  const int NOUT = NC*gridDim.y;
  #pragma unroll
  for (int i = 0; i < 4; i++){
    #pragma unroll
    for (int j = 0; j < NI; j++){
      int col = col0 + j*16;
      float bv = bias[col];
      #pragma unroll
      for (int r = 0; r < 4; r++){
        int row = row0 + i*16 + r;
        float v = acc[i][j][r] + bv;
        if (RELU) v = fmaxf(v, 0.f);
        if (ADDOUT) v = v + ((const float*)out)[(size_t)row*NOUT + col];
        if (OUTBF16) ((unsigned short*)out)[(size_t)row*NOUT + col] = f2bf(v);
        else         ((float*)out)[(size_t)row*NOUT + col] = v;
      }
    }
  }
}

// ================= KNN via uniform grid (counting sort + shell search) ======
#define GD 14
#define GD3 (GD*GD*GD)          // 2744 cells, ~3 pts/cell
#define NL 8192

__device__ __forceinline__ int cellcoord(float x){
  int c = (int)(x * (float)GD);
  return min(GD-1, max(0, c));
}

__global__ __launch_bounds__(64) void k_zero(int* __restrict__ p){
  #pragma unroll
  for (int i = 0; i < 16; i++)
    ((int4*)p)[threadIdx.x*16 + i] = (int4){0,0,0,0};
}

__global__ __launch_bounds__(256) void k_hist(const float* __restrict__ l_pos,
                                              int* __restrict__ hist){
  int i = blockIdx.x*256 + threadIdx.x;       // exactly 8192 threads
  float x = l_pos[3*i], y = l_pos[3*i+1], z = l_pos[3*i+2];
  int c = (cellcoord(z)*GD + cellcoord(y))*GD + cellcoord(x);
  atomicAdd(&hist[c], 1);
}

__global__ __launch_bounds__(1024) void k_scan(const int* __restrict__ hist,
                                               int* __restrict__ cellStart,
                                               int* __restrict__ cursor){
  __shared__ int s[1024];
  int t = threadIdx.x;
  int4 v = ((const int4*)hist)[t];
  int sum = v.x + v.y + v.z + v.w;
  s[t] = sum;
  __syncthreads();
  for (int off = 1; off < 1024; off <<= 1){
    int val = (t >= off) ? s[t-off] : 0;
    __syncthreads();
    s[t] += val;
    __syncthreads();
  }
  int base = s[t] - sum;
  int4 cs;
  cs.x = base;
  cs.y = base + v.x;
  cs.z = base + v.x + v.y;
  cs.w = base + v.x + v.y + v.z;
  ((int4*)cellStart)[t] = cs;
  ((int4*)cursor)[t]    = cs;
}

__global__ __launch_bounds__(256) void k_scatter(const float* __restrict__ l_pos,
                                                 int* __restrict__ cursor,
                                                 float4* __restrict__ sorted){
  int i = blockIdx.x*256 + threadIdx.x;       // exactly 8192 threads
  float x = l_pos[3*i], y = l_pos[3*i+1], z = l_pos[3*i+2];
  int c = (cellcoord(z)*GD + cellcoord(y))*GD + cellcoord(x);
  int slot = atomicAdd(&cursor[c], 1);
  float4 q; q.x = x; q.y = y; q.z = z; q.w = __int_as_float(i);
  sorted[slot] = q;
}

// Dedup-safe + (d, index)-lexicographic insert: order-independent top-3
#define KNN_INS(dv, gi) \
  if (gi != i0 && gi != i1 && gi != i2 && \
      (dv < d2 || (dv == d2 && gi < i2))){ \
    if (dv < d1 || (dv == d1 && gi < i1)){ \
      d2 = d1; i2 = i1; \
      if (dv < d0 || (dv == d0 && gi < i0)){ d1 = d0; i1 = i0; d0 = dv; i0 = gi; } \
      else { d1 = dv; i1 = gi; } \
    } else { d2 = dv; i2 = gi; } \
  }

#define KNN_MERGE16() \
  _Pragma("unroll") \
  for (int m = 1; m < 16; m <<= 1){ \
    float e0 = __shfl_xor(d0, m), e1 = __shfl_xor(d1, m), e2 = __shfl_xor(d2, m); \
    int   j0 = __shfl_xor(i0, m), j1 = __shfl_xor(i1, m), j2 = __shfl_xor(i2, m); \
    KNN_INS(e0, j0); KNN_INS(e1, j1); KNN_INS(e2, j2); \
  }

// 16 lanes cooperate per h-point: 524288 threads = 8192 waves = 32 waves/CU
__global__ __launch_bounds__(256) void k_knn_grid(const float* __restrict__ h_pos,
                                                  const int* __restrict__ cellStart,
                                                  const float4* __restrict__ sorted,
                                                  float* __restrict__ w,
                                                  int* __restrict__ idx){
  const int t = blockIdx.x*256 + threadIdx.x;
  const int h = t >> 4, sl = t & 15;
  const float hx = h_pos[3*h], hy = h_pos[3*h+1], hz = h_pos[3*h+2];
  const int cx = cellcoord(hx), cy = cellcoord(hy), cz = cellcoord(hz);
  const float cs = 1.0f/(float)GD;
  float d0 = 3e38f, d1 = 3e38f, d2 = 3e38f;
  int   i0 = 0x7fffffff, i1 = 0x7fffffff, i2 = 0x7fffffff;

  for (int ci = sl; ci < 27; ci += 16){
    int dz = ci/9 - 1, dy = (ci - (ci/9)*9)/3 - 1, dx = ci % 3 - 1;
    int zz = cz+dz, yy = cy+dy, xx = cx+dx;
    if ((unsigned)zz >= GD || (unsigned)yy >= GD || (unsigned)xx >= GD) continue;
    int c = (zz*GD + yy)*GD + xx;
    int p0 = cellStart[c], p1 = cellStart[c+1];
    for (int p = p0; p < p1; p++){
      float4 qq = sorted[p];
      float ddx = hx - qq.x, ddy = hy - qq.y, ddz = hz - qq.z;
      float d = fmaf(ddx, ddx, fmaf(ddy, ddy, ddz*ddz));
      int gi = __float_as_int(qq.w);
      KNN_INS(d, gi);
    }
  }
  KNN_MERGE16();

  for (int r = 2; r < GD; r++){
    int rp = r - 1;
    float B = 3e38f;
    if (cx - rp > 0)      B = fminf(B, hx - (float)(cx-rp)*cs);
    if (cx + rp + 1 < GD) B = fminf(B, (float)(cx+rp+1)*cs - hx);
    if (cy - rp > 0)      B = fminf(B, hy - (float)(cy-rp)*cs);
    if (cy + rp + 1 < GD) B = fminf(B, (float)(cy+rp+1)*cs - hy);
    if (cz - rp > 0)      B = fminf(B, hz - (float)(cz-rp)*cs);
    if (cz + rp + 1 < GD) B = fminf(B, (float)(cz+rp+1)*cs - hz);
    if (d2 <= B*B) break;                     // group-uniform after merge

    int side = 2*r + 1, ss = side*side, tot = ss*side;
    for (int ci = sl; ci < tot; ci += 16){
      int dz = ci/ss - r;
      int rem = ci - (ci/ss)*ss;
      int dy = rem/side - r, dx = rem - (rem/side)*side - r;
      int adx = abs(dx), ady = abs(dy), adz = abs(dz);
      if (max(adx, max(ady, adz)) < r) continue;   // shell-exact: skip interior
      int zz = cz+dz, yy = cy+dy, xx = cx+dx;
      if ((unsigned)zz >= GD || (unsigned)yy >= GD || (unsigned)xx >= GD) continue;
      int c = (zz*GD + yy)*GD + xx;
      int p0 = cellStart[c], p1 = cellStart[c+1];
      for (int p = p0; p < p1; p++){
        float4 qq = sorted[p];
        float ddx = hx - qq.x, ddy = hy - qq.y, ddz = hz - qq.z;
        float d = fmaf(ddx, ddx, fmaf(ddy, ddy, ddz*ddz));
        int gi = __float_as_int(qq.w);
        KNN_INS(d, gi);
      }
    }
    KNN_MERGE16();
  }

  if (sl == 0){
    w[3*h+0] = 1.0f/fmaxf(d0, 1e-16f); idx[3*h+0] = i0;
    w[3*h+1] = 1.0f/fmaxf(d1, 1e-16f); idx[3*h+1] = i1;
    w[3*h+2] = 1.0f/fmaxf(d2, 1e-16f); idx[3*h+2] = i2;
  }
}

// ---------- KNN gather: WRITES interp into out (GEMM3 adds on top) ----------
__global__ __launch_bounds__(256) void k_knn_gather(const float* __restrict__ w,
                                                    const int* __restrict__ idx,
                                                    const float* __restrict__ l_y,
                                                    float* __restrict__ out){
  const int t = blockIdx.x*256 + threadIdx.x;
  const int h = t >> 5, lane = t & 31;               // 32 lanes x float4 = 128 feats
  const float w0 = w[h*3+0], w1 = w[h*3+1], w2 = w[h*3+2];
  const int   j0 = idx[h*3+0], j1 = idx[h*3+1], j2 = idx[h*3+2];
  const f32x4* ly4 = (const f32x4*)l_y;
  f32x4 a = ly4[(size_t)j0*32 + lane]*w0
          + ly4[(size_t)j1*32 + lane]*w1
          + ly4[(size_t)j2*32 + lane]*w2;
  float inv = 1.0f/(w0 + w1 + w2);
  ((f32x4*)out)[(size_t)h*32 + lane] = a*inv;
}

extern "C" void kernel_launch(void* const* d_in, const int* in_sizes, int n_in,
                              void* d_out, int out_size, void* d_ws, size_t ws_size,
                              hipStream_t stream){
  const float* emb   = (const float*)d_in[0];
  const float* l_y   = (const float*)d_in[1];
  const float* l_pos = (const float*)d_in[2];
  const float* h_pos = (const float*)d_in[3];
  const float* W1    = (const float*)d_in[4];
  const float* b1    = (const float*)d_in[5];
  const float* W2    = (const float*)d_in[6];
  const float* b2    = (const float*)d_in[7];
  const float* W3    = (const float*)d_in[8];
  const float* b3    = (const float*)d_in[9];

  const int M = 32768, H = 512;

  char* ws = (char*)d_ws;
  unsigned short* bufA = (unsigned short*)(ws);                  // 32 MB: X2
  unsigned short* bufB = (unsigned short*)(ws + 33554432);       // 32 MB: X1
  unsigned short* W1t  = (unsigned short*)(ws + 67108864);       // 512 KB
  unsigned short* W2t  = (unsigned short*)(ws + 67633152);       // 512 KB
  unsigned short* W3t  = (unsigned short*)(ws + 68157440);       // 128 KB
  int*    hist      = (int*)   (ws + 68288512);                  // 16 KB (4096 padded)
  int*    cellStart = (int*)   (ws + 68304896);                  // 16 KB
  int*    cursor    = (int*)   (ws + 68321280);                  // 16 KB
  float4* sorted    = (float4*)(ws + 68354048);                  // 128 KB
  float* wts = (float*)(ws + 74579968);                          // 384 KB
  int*   idx = (int*)  (ws + 74973184);                          // 384 KB

  // weight transposes (batched) — bf16 [N][K] for MFMA B-operand
  k_transpose3<<<dim3(16, 16, 3), 256, 0, stream>>>(W1, W2, W3, W1t, W2t, W3t);

  // KNN interpolate first; gather WRITES d_out (GEMM3 adds on top)
  k_zero<<<dim3(1), 64, 0, stream>>>(hist);
  k_hist<<<dim3(NL/256), 256, 0, stream>>>(l_pos, hist);
  k_scan<<<dim3(1), 1024, 0, stream>>>(hist, cellStart, cursor);
  k_scatter<<<dim3(NL/256), 256, 0, stream>>>(l_pos, cursor, sorted);
  k_knn_grid<<<dim3(M*16/256), 256, 0, stream>>>(h_pos, cellStart, sorted, wts, idx);
  k_knn_gather<<<dim3(M*32/256), 256, 0, stream>>>(wts, idx, l_y, (float*)d_out);

  // MLP: 2 blocks/CU for cross-block latency hiding
  k_gemm<128, 256, 512, 4, true,  true,  true,  false><<<dim3(M/128, 2), 512, 0, stream>>>(emb,  W1t, b1, bufB, H);
  k_gemm<128, 256, 512, 4, false, true,  true,  false><<<dim3(M/128, 2), 512, 0, stream>>>(bufB, W2t, b2, bufA, H);
  k_gemm<64,  128, 256, 2, false, false, false, true ><<<dim3(M/64,  1), 256, 0, stream>>>(bufA, W3t, b3, d_out, H);
}